// Round 8
// baseline (416.126 us; speedup 1.0000x reference)
//
#include <hip/hip_runtime.h>

#define SEQ 128
#define BSZ 64
#define EMB 32
#define HD  8
#define VOC 32000
#define NPOS (SEQ * BSZ)          // 8192 positions
#define NRB  (NPOS / 32)          // 256 row-blocks of 32 positions
#define NTILE (VOC / 32)          // 1000 v-tiles
#define TPW  (NTILE / 8)          // 125 tiles per wave (8 waves/block)
#define LOG2E 1.4426950408889634f
#define LN2   0.6931471805599453f

typedef float f32x4  __attribute__((ext_vector_type(4)));
typedef short bf16x8 __attribute__((ext_vector_type(8)));
typedef float f32x16 __attribute__((ext_vector_type(16)));

// round-to-nearest-even f32 -> bf16 bits
__device__ __forceinline__ unsigned short f2bf(float f) {
    union { float f; unsigned int u; } x; x.f = f;
    unsigned int r = x.u + 0x7fffu + ((x.u >> 16) & 1u);
    return (unsigned short)(r >> 16);
}

// ---------------------------------------------------------------------------
// Kernel A (fused prep):
//  blocks [0,32):    xproj = lookup[idx] @ Wx + b1 + b2 (both dirs),
//                    thread-contiguous, backward copy time-reversed.
//  blocks [32,157):  wt2 = bf16(Wo^T * log2e)  [32000][16];  bo2 = bo * log2e
// ---------------------------------------------------------------------------
__global__ __launch_bounds__(256) void prep_kernel(
    const int*   __restrict__ idx,
    const float* __restrict__ lookup,
    const float* __restrict__ Wxf, const float* __restrict__ Wxb,
    const float* __restrict__ bf1, const float* __restrict__ bf2,
    const float* __restrict__ bb1, const float* __restrict__ bb2,
    const float* __restrict__ Wo,  const float* __restrict__ bo,
    float* __restrict__ xpf, float* __restrict__ xpb,
    unsigned short* __restrict__ wt2, float* __restrict__ bo2)
{
    if (blockIdx.x < 32) {
        const int i = blockIdx.x * 256 + threadIdx.x;   // flat (s*B + b)
        const int s = i >> 6;
        const int b = i & 63;

        const float* xr = lookup + (size_t)idx[i] * EMB;
        float x[EMB];
#pragma unroll
        for (int e = 0; e < EMB; ++e) x[e] = xr[e];

#pragma unroll
        for (int h = 0; h < HD; ++h) {
            float af = bf1[h] + bf2[h];
            float ab = bb1[h] + bb2[h];
#pragma unroll
            for (int e = 0; e < EMB; ++e) {
                af = fmaf(x[e], Wxf[e * HD + h], af);
                ab = fmaf(x[e], Wxb[e * HD + h], ab);
            }
            xpf[(b * HD + h) * SEQ + s]             = af;
            xpb[(b * HD + h) * SEQ + (SEQ - 1 - s)] = ab;
        }
    } else {
        const int v = (blockIdx.x - 32) * 256 + threadIdx.x;
        if (v < VOC) {
#pragma unroll
            for (int k = 0; k < 16; ++k)
                wt2[v * 16 + k] = f2bf(Wo[k * VOC + v] * LOG2E);
            bo2[v] = bo[v] * LOG2E;
        }
    }
}

// ---------------------------------------------------------------------------
// Kernel B: serial recurrence, pure-register; emits bf16 Hcat (hc2[pos][16]).
// ---------------------------------------------------------------------------
__global__ __launch_bounds__(512) void rnn_scan_kernel(
    const float* __restrict__ xpf, const float* __restrict__ xpb,
    const float* __restrict__ Whf, const float* __restrict__ Whb,
    const float* __restrict__ Hf0, const float* __restrict__ Hb0,
    unsigned short* __restrict__ hc2)
{
    const int dir = blockIdx.x;
    const int tid = threadIdx.x;
    const int b   = tid >> 3;
    const int h   = tid & 7;

    const float* Wh = dir ? Whb : Whf;
    const float* xp = (dir ? xpb : xpf) + (size_t)tid * SEQ;

    float wh[HD];
#pragma unroll
    for (int j = 0; j < HD; ++j) wh[j] = Wh[j * HD + h];

    float xs[SEQ];
    const f32x4* xp4 = (const f32x4*)xp;
#pragma unroll
    for (int q = 0; q < SEQ / 4; ++q) {
        f32x4 v = xp4[q];
        xs[4 * q + 0] = v.x; xs[4 * q + 1] = v.y;
        xs[4 * q + 2] = v.z; xs[4 * q + 3] = v.w;
    }

    float hcur = dir ? Hb0[h] : Hf0[h];
    const int koff = dir ? HD : 0;

#pragma unroll
    for (int t = 0; t < SEQ; ++t) {
        const int s = dir ? (SEQ - 1 - t) : t;
        hc2[(s * BSZ + b) * 16 + koff + h] = f2bf(hcur);   // previous state

        float acc = xs[t];
#pragma unroll
        for (int j = 0; j < HD; ++j)
            acc = fmaf(__shfl(hcur, j, 8), wh[j], acc);

        float e = __expf(2.0f * acc);
        hcur = (e - 1.0f) / (e + 1.0f);
    }
}

// ---------------------------------------------------------------------------
// Kernel C (fused LSE + output): one block (512 thr, 8 waves) per 32-row
// block. Wave w owns v-tiles [w*125, (w+1)*125).
//   pass 1: MFMA(scaled wt2) -> exp2f -> per-row partial sums
//           -> in-wave shfl reduce -> LDS -> 32-thread block reduce -> logf.
//   pass 2: MFMA again, val = fma(d + bo2, ln2, -lse), nontemporal store.
// No inter-block dependency: a block starts writing as soon as ITS lse is
// ready. Weights are read only from wt2 (1 MB, L2-resident).
// MFMA 32x32x16 bf16 D layout: col=lane&31, row=(g&3)+8*(g>>2)+4*(lane>>5).
// ---------------------------------------------------------------------------
__global__ __launch_bounds__(512) void fused_out_kernel(
    const unsigned short* __restrict__ hc2,
    const unsigned short* __restrict__ wt2,
    const float* __restrict__ bo2,
    float* __restrict__ out)
{
    __shared__ float lds_sum[8][32];
    __shared__ float lds_lse[32];

    const int tid  = threadIdx.x;
    const int w    = tid >> 6;         // wave 0..7
    const int lane = tid & 63;
    const int half = lane >> 5;
    const int lc   = lane & 31;
    const int rb   = blockIdx.x;

    const bf16x8 afrag = *(const bf16x8*)(hc2 + (size_t)(rb * 32 + lc) * 16 + half * 8);

    f32x16 zv;
#pragma unroll
    for (int i = 0; i < 16; ++i) zv[i] = 0.0f;

    // ---- pass 1: partial exp2 sums over this wave's 125 tiles ----
    float sacc[16];
#pragma unroll
    for (int g = 0; g < 16; ++g) sacc[g] = 0.0f;

#pragma unroll 2
    for (int t = 0; t < TPW; ++t) {
        const int v0 = (w * TPW + t) * 32;
        const bf16x8 bfrag = *(const bf16x8*)(wt2 + (size_t)(v0 + lc) * 16 + half * 8);
        f32x16 d = __builtin_amdgcn_mfma_f32_32x32x16_bf16(afrag, bfrag, zv, 0, 0, 0);
        const float bov = bo2[v0 + lc];
#pragma unroll
        for (int g = 0; g < 16; ++g)
            sacc[g] += exp2f(d[g] + bov);
    }

    // in-wave reduce across the 32 lanes of each half
#pragma unroll
    for (int g = 0; g < 16; ++g) {
        float s = sacc[g];
        s += __shfl_xor(s, 1, 32);
        s += __shfl_xor(s, 2, 32);
        s += __shfl_xor(s, 4, 32);
        s += __shfl_xor(s, 8, 32);
        s += __shfl_xor(s, 16, 32);
        sacc[g] = s;
    }
    if (lc == 0) {
#pragma unroll
        for (int g = 0; g < 16; ++g) {
            const int row = (g & 3) + 8 * (g >> 2) + 4 * half;
            lds_sum[w][row] = sacc[g];
        }
    }
    __syncthreads();

    // block reduce over the 8 waves (fixed order -> deterministic)
    if (tid < 32) {
        float s = 0.0f;
#pragma unroll
        for (int ww = 0; ww < 8; ++ww) s += lds_sum[ww][tid];
        lds_lse[tid] = logf(s);
    }
    __syncthreads();

    float nls[16];
#pragma unroll
    for (int g = 0; g < 16; ++g) {
        const int row = (g & 3) + 8 * (g >> 2) + 4 * half;
        nls[g] = -lds_lse[row];
    }

    // ---- pass 2: recompute logits, write log_softmax (nontemporal) ----
#pragma unroll 2
    for (int t = 0; t < TPW; ++t) {
        const int v0 = (w * TPW + t) * 32;
        const bf16x8 bfrag = *(const bf16x8*)(wt2 + (size_t)(v0 + lc) * 16 + half * 8);
        f32x16 d = __builtin_amdgcn_mfma_f32_32x32x16_bf16(afrag, bfrag, zv, 0, 0, 0);
        const float bov = bo2[v0 + lc];
#pragma unroll
        for (int g = 0; g < 16; ++g) {
            const int row = (g & 3) + 8 * (g >> 2) + 4 * half;
            const float val = fmaf(d[g] + bov, LN2, nls[g]);
            __builtin_nontemporal_store(
                val, out + (size_t)(rb * 32 + row) * VOC + v0 + lc);
        }
    }
}

extern "C" void kernel_launch(void* const* d_in, const int* in_sizes, int n_in,
                              void* d_out, int out_size, void* d_ws, size_t ws_size,
                              hipStream_t stream)
{
    const int*   idx    = (const int*)  d_in[0];
    const float* lookup = (const float*)d_in[1];
    const float* Wxf    = (const float*)d_in[2];
    const float* Whf    = (const float*)d_in[3];
    const float* Wxb    = (const float*)d_in[4];
    const float* Whb    = (const float*)d_in[5];
    const float* Wo     = (const float*)d_in[6];
    const float* Hf0    = (const float*)d_in[7];
    const float* Hb0    = (const float*)d_in[8];
    const float* bf1    = (const float*)d_in[9];
    const float* bf2    = (const float*)d_in[10];
    const float* bb1    = (const float*)d_in[11];
    const float* bb2    = (const float*)d_in[12];
    const float* bo     = (const float*)d_in[13];
    float* out = (float*)d_out;

    // workspace layout (all 16B-aligned)
    char* ws = (char*)d_ws;
    float*          xpf = (float*)ws;          ws += BSZ * HD * SEQ * 4;   // 256 KB
    float*          xpb = (float*)ws;          ws += BSZ * HD * SEQ * 4;   // 256 KB
    unsigned short* hc2 = (unsigned short*)ws; ws += NPOS * 16 * 2;        // 256 KB
    unsigned short* wt2 = (unsigned short*)ws; ws += VOC * 16 * 2;         // 1 MB
    float*          bo2 = (float*)ws;          ws += VOC * 4;              // 128 KB

    hipLaunchKernelGGL(prep_kernel, dim3(32 + VOC / 256), dim3(256), 0, stream,
                       idx, lookup, Wxf, Wxb, bf1, bf2, bb1, bb2, Wo, bo,
                       xpf, xpb, wt2, bo2);
    hipLaunchKernelGGL(rnn_scan_kernel, dim3(2), dim3(512), 0, stream,
                       xpf, xpb, Whf, Whb, Hf0, Hb0, hc2);
    hipLaunchKernelGGL(fused_out_kernel, dim3(NRB), dim3(512), 0, stream,
                       hc2, wt2, bo2, out);
}

// Round 9
// 290.843 us; speedup vs baseline: 1.4308x; 1.4308x over previous
//
#include <hip/hip_runtime.h>

#define SEQ 128
#define BSZ 64
#define EMB 32
#define HD  8
#define VOC 32000
#define NPOS (SEQ * BSZ)          // 8192 positions
#define NRB  (NPOS / 32)          // 256 row-blocks of 32 positions
#define NVS  40                   // v-splits; 1000 v-tiles = 40 * 25
#define TPW  25                   // v-tiles per wave

typedef float f32x4  __attribute__((ext_vector_type(4)));
typedef short bf16x8 __attribute__((ext_vector_type(8)));
typedef float f32x16 __attribute__((ext_vector_type(16)));

// round-to-nearest-even f32 -> bf16 bits
__device__ __forceinline__ unsigned short f2bf(float f) {
    union { float f; unsigned int u; } x; x.f = f;
    unsigned int r = x.u + 0x7fffu + ((x.u >> 16) & 1u);
    return (unsigned short)(r >> 16);
}

// ---------------------------------------------------------------------------
// Kernel A (fused prep):
//  blocks [0,32):   xproj = lookup[idx] @ Wx + b1 + b2 (both dirs),
//                   thread-contiguous, backward copy time-reversed.
//  blocks [32,157): wt = bf16(Wo^T)  [32000][16]
// ---------------------------------------------------------------------------
__global__ __launch_bounds__(256) void prep_kernel(
    const int*   __restrict__ idx,
    const float* __restrict__ lookup,
    const float* __restrict__ Wxf, const float* __restrict__ Wxb,
    const float* __restrict__ bf1, const float* __restrict__ bf2,
    const float* __restrict__ bb1, const float* __restrict__ bb2,
    const float* __restrict__ Wo,
    float* __restrict__ xpf, float* __restrict__ xpb,
    unsigned short* __restrict__ wt)
{
    if (blockIdx.x < 32) {
        const int i = blockIdx.x * 256 + threadIdx.x;   // flat (s*B + b)
        const int s = i >> 6;
        const int b = i & 63;

        const float* xr = lookup + (size_t)idx[i] * EMB;
        float x[EMB];
#pragma unroll
        for (int e = 0; e < EMB; ++e) x[e] = xr[e];

#pragma unroll
        for (int h = 0; h < HD; ++h) {
            float af = bf1[h] + bf2[h];
            float ab = bb1[h] + bb2[h];
#pragma unroll
            for (int e = 0; e < EMB; ++e) {
                af = fmaf(x[e], Wxf[e * HD + h], af);
                ab = fmaf(x[e], Wxb[e * HD + h], ab);
            }
            xpf[(b * HD + h) * SEQ + s]             = af;
            xpb[(b * HD + h) * SEQ + (SEQ - 1 - s)] = ab;
        }
    } else {
        const int v = (blockIdx.x - 32) * 256 + threadIdx.x;
        if (v < VOC) {
#pragma unroll
            for (int k = 0; k < 16; ++k)
                wt[v * 16 + k] = f2bf(Wo[k * VOC + v]);
        }
    }
}

// ---------------------------------------------------------------------------
// Kernel B: serial recurrence, pure-register; emits bf16 Hcat (hc2[pos][16]).
// ---------------------------------------------------------------------------
__global__ __launch_bounds__(512) void rnn_scan_kernel(
    const float* __restrict__ xpf, const float* __restrict__ xpb,
    const float* __restrict__ Whf, const float* __restrict__ Whb,
    const float* __restrict__ Hf0, const float* __restrict__ Hb0,
    unsigned short* __restrict__ hc2)
{
    const int dir = blockIdx.x;
    const int tid = threadIdx.x;
    const int b   = tid >> 3;
    const int h   = tid & 7;

    const float* Wh = dir ? Whb : Whf;
    const float* xp = (dir ? xpb : xpf) + (size_t)tid * SEQ;

    float wh[HD];
#pragma unroll
    for (int j = 0; j < HD; ++j) wh[j] = Wh[j * HD + h];

    float xs[SEQ];
    const f32x4* xp4 = (const f32x4*)xp;
#pragma unroll
    for (int q = 0; q < SEQ / 4; ++q) {
        f32x4 v = xp4[q];
        xs[4 * q + 0] = v.x; xs[4 * q + 1] = v.y;
        xs[4 * q + 2] = v.z; xs[4 * q + 3] = v.w;
    }

    float hcur = dir ? Hb0[h] : Hf0[h];
    const int koff = dir ? HD : 0;

#pragma unroll
    for (int t = 0; t < SEQ; ++t) {
        const int s = dir ? (SEQ - 1 - t) : t;
        hc2[(s * BSZ + b) * 16 + koff + h] = f2bf(hcur);   // previous state

        float acc = xs[t];
#pragma unroll
        for (int j = 0; j < HD; ++j)
            acc = fmaf(__shfl(hcur, j, 8), wh[j], acc);

        float e = __expf(2.0f * acc);
        hcur = (e - 1.0f) / (e + 1.0f);
    }
}

// ---------------------------------------------------------------------------
// Kernel C: partial exp-sums. Wave = (row-block rb, v-split vs); 25 v-tiles.
// MFMA 32x32x16 bf16 D layout: col=lane&31, row=(g&3)+8*(g>>2)+4*(lane>>5).
// ---------------------------------------------------------------------------
__global__ __launch_bounds__(256) void lse_partial_kernel(
    const unsigned short* __restrict__ hc2,
    const unsigned short* __restrict__ wt,
    const float* __restrict__ bo,
    float* __restrict__ partial)
{
    const int gw   = blockIdx.x * 4 + (threadIdx.x >> 6);   // global wave id
    const int rb   = gw / NVS;
    const int vs   = gw - rb * NVS;
    const int lane = threadIdx.x & 63;
    const int half = lane >> 5;
    const int lc   = lane & 31;

    const bf16x8 afrag = *(const bf16x8*)(hc2 + (size_t)(rb * 32 + lc) * 16 + half * 8);

    f32x16 zv;
#pragma unroll
    for (int i = 0; i < 16; ++i) zv[i] = 0.0f;

    float sacc[16];
#pragma unroll
    for (int g = 0; g < 16; ++g) sacc[g] = 0.0f;

    for (int t = 0; t < TPW; ++t) {
        const int v0 = (vs * TPW + t) * 32;
        const bf16x8 bfrag = *(const bf16x8*)(wt + (size_t)(v0 + lc) * 16 + half * 8);
        f32x16 d = __builtin_amdgcn_mfma_f32_32x32x16_bf16(afrag, bfrag, zv, 0, 0, 0);
        const float bov = bo[v0 + lc];
#pragma unroll
        for (int g = 0; g < 16; ++g)
            sacc[g] += __expf(d[g] + bov);
    }

    // reduce each sacc[g] across the 32 lanes of this half
#pragma unroll
    for (int g = 0; g < 16; ++g) {
        float s = sacc[g];
        s += __shfl_xor(s, 1, 32);
        s += __shfl_xor(s, 2, 32);
        s += __shfl_xor(s, 4, 32);
        s += __shfl_xor(s, 8, 32);
        s += __shfl_xor(s, 16, 32);
        sacc[g] = s;
    }

    if (lc == 0) {
#pragma unroll
        for (int g = 0; g < 16; ++g) {
            const int row = (g & 3) + 8 * (g >> 2) + 4 * half;
            partial[(size_t)(rb * 32 + row) * NVS + vs] = sacc[g];
        }
    }
}

// ---------------------------------------------------------------------------
// Kernel D: lse[row] = log( sum_vs partial[row][vs] )
// ---------------------------------------------------------------------------
__global__ __launch_bounds__(256) void lse_reduce_kernel(
    const float* __restrict__ partial, float* __restrict__ lse)
{
    const int row = blockIdx.x * 256 + threadIdx.x;
    if (row >= NPOS) return;
    const f32x4* p4 = (const f32x4*)(partial + (size_t)row * NVS);
    float s = 0.0f;
#pragma unroll
    for (int q = 0; q < NVS / 4; ++q) {
        f32x4 v = p4[q];
        s += v.x + v.y + v.z + v.w;
    }
    lse[row] = logf(s);
}

// ---------------------------------------------------------------------------
// Kernel E: out = logits - lse, recomputed via MFMA, nontemporal stores.
// Same wave decomposition as kernel C.
// ---------------------------------------------------------------------------
__global__ __launch_bounds__(256) void out_mfma_kernel(
    const unsigned short* __restrict__ hc2,
    const unsigned short* __restrict__ wt,
    const float* __restrict__ bo,
    const float* __restrict__ lse,
    float* __restrict__ out)
{
    const int gw   = blockIdx.x * 4 + (threadIdx.x >> 6);
    const int rb   = gw / NVS;
    const int vs   = gw - rb * NVS;
    const int lane = threadIdx.x & 63;
    const int half = lane >> 5;
    const int lc   = lane & 31;

    const bf16x8 afrag = *(const bf16x8*)(hc2 + (size_t)(rb * 32 + lc) * 16 + half * 8);

    f32x16 zv;
#pragma unroll
    for (int i = 0; i < 16; ++i) zv[i] = 0.0f;

    // per-lane lse for its 16 (reg) rows
    float lse16[16];
#pragma unroll
    for (int g = 0; g < 16; ++g) {
        const int row = (g & 3) + 8 * (g >> 2) + 4 * half;
        lse16[g] = lse[rb * 32 + row];
    }

    for (int t = 0; t < TPW; ++t) {
        const int v0 = (vs * TPW + t) * 32;
        const bf16x8 bfrag = *(const bf16x8*)(wt + (size_t)(v0 + lc) * 16 + half * 8);
        f32x16 d = __builtin_amdgcn_mfma_f32_32x32x16_bf16(afrag, bfrag, zv, 0, 0, 0);
        const float bov = bo[v0 + lc];
#pragma unroll
        for (int g = 0; g < 16; ++g) {
            const int row = (g & 3) + 8 * (g >> 2) + 4 * half;
            const float val = d[g] + bov - lse16[g];
            __builtin_nontemporal_store(
                val, out + (size_t)(rb * 32 + row) * VOC + v0 + lc);
        }
    }
}

extern "C" void kernel_launch(void* const* d_in, const int* in_sizes, int n_in,
                              void* d_out, int out_size, void* d_ws, size_t ws_size,
                              hipStream_t stream)
{
    const int*   idx    = (const int*)  d_in[0];
    const float* lookup = (const float*)d_in[1];
    const float* Wxf    = (const float*)d_in[2];
    const float* Whf    = (const float*)d_in[3];
    const float* Wxb    = (const float*)d_in[4];
    const float* Whb    = (const float*)d_in[5];
    const float* Wo     = (const float*)d_in[6];
    const float* Hf0    = (const float*)d_in[7];
    const float* Hb0    = (const float*)d_in[8];
    const float* bf1    = (const float*)d_in[9];
    const float* bf2    = (const float*)d_in[10];
    const float* bb1    = (const float*)d_in[11];
    const float* bb2    = (const float*)d_in[12];
    const float* bo     = (const float*)d_in[13];
    float* out = (float*)d_out;

    // workspace layout (all 16B-aligned)
    char* ws = (char*)d_ws;
    float*          xpf     = (float*)ws;          ws += BSZ * HD * SEQ * 4;      // 256 KB
    float*          xpb     = (float*)ws;          ws += BSZ * HD * SEQ * 4;      // 256 KB
    unsigned short* hc2     = (unsigned short*)ws; ws += NPOS * 16 * 2;           // 256 KB
    unsigned short* wt      = (unsigned short*)ws; ws += VOC * 16 * 2;            // 1 MB
    float*          partial = (float*)ws;          ws += (size_t)NPOS * NVS * 4;  // 1.31 MB
    float*          lse     = (float*)ws;          ws += NPOS * 4;                // 32 KB

    hipLaunchKernelGGL(prep_kernel, dim3(32 + VOC / 256), dim3(256), 0, stream,
                       idx, lookup, Wxf, Wxb, bf1, bf2, bb1, bb2, Wo,
                       xpf, xpb, wt);
    hipLaunchKernelGGL(rnn_scan_kernel, dim3(2), dim3(512), 0, stream,
                       xpf, xpb, Whf, Whb, Hf0, Hb0, hc2);
    hipLaunchKernelGGL(lse_partial_kernel, dim3(NRB * NVS / 4), dim3(256), 0, stream,
                       hc2, wt, bo, partial);
    hipLaunchKernelGGL(lse_reduce_kernel, dim3(NPOS / 256), dim3(256), 0, stream,
                       partial, lse);
    hipLaunchKernelGGL(out_mfma_kernel, dim3(NRB * NVS / 4), dim3(256), 0, stream,
                       hc2, wt, bo, lse, out);
}

// Round 10
// 287.082 us; speedup vs baseline: 1.4495x; 1.0131x over previous
//
#include <hip/hip_runtime.h>

#define SEQ 128
#define BSZ 64
#define EMB 32
#define HD  8
#define VOC 32000
#define NPOS (SEQ * BSZ)          // 8192 positions
#define NRB  (NPOS / 32)          // 256 row-blocks of 32 positions
#define NVS  40                   // v-splits; 1000 v-tiles = 40 * 25
#define TPW  25                   // v-tiles per wave

typedef float f32x4  __attribute__((ext_vector_type(4)));
typedef short bf16x8 __attribute__((ext_vector_type(8)));
typedef float f32x16 __attribute__((ext_vector_type(16)));

// round-to-nearest-even f32 -> bf16 bits
__device__ __forceinline__ unsigned short f2bf(float f) {
    union { float f; unsigned int u; } x; x.f = f;
    unsigned int r = x.u + 0x7fffu + ((x.u >> 16) & 1u);
    return (unsigned short)(r >> 16);
}

// ---------------------------------------------------------------------------
// Kernel A (fused prep):
//  blocks [0,32):   xproj = lookup[idx] @ Wx + b1 + b2 (both dirs),
//                   thread-contiguous, backward copy time-reversed.
//  blocks [32,157): wt = bf16(Wo^T)  [32000][16]
// ---------------------------------------------------------------------------
__global__ __launch_bounds__(256) void prep_kernel(
    const int*   __restrict__ idx,
    const float* __restrict__ lookup,
    const float* __restrict__ Wxf, const float* __restrict__ Wxb,
    const float* __restrict__ bf1, const float* __restrict__ bf2,
    const float* __restrict__ bb1, const float* __restrict__ bb2,
    const float* __restrict__ Wo,
    float* __restrict__ xpf, float* __restrict__ xpb,
    unsigned short* __restrict__ wt)
{
    if (blockIdx.x < 32) {
        const int i = blockIdx.x * 256 + threadIdx.x;   // flat (s*B + b)
        const int s = i >> 6;
        const int b = i & 63;

        const float* xr = lookup + (size_t)idx[i] * EMB;
        float x[EMB];
#pragma unroll
        for (int e = 0; e < EMB; ++e) x[e] = xr[e];

#pragma unroll
        for (int h = 0; h < HD; ++h) {
            float af = bf1[h] + bf2[h];
            float ab = bb1[h] + bb2[h];
#pragma unroll
            for (int e = 0; e < EMB; ++e) {
                af = fmaf(x[e], Wxf[e * HD + h], af);
                ab = fmaf(x[e], Wxb[e * HD + h], ab);
            }
            xpf[(b * HD + h) * SEQ + s]             = af;
            xpb[(b * HD + h) * SEQ + (SEQ - 1 - s)] = ab;
        }
    } else {
        const int v = (blockIdx.x - 32) * 256 + threadIdx.x;
        if (v < VOC) {
#pragma unroll
            for (int k = 0; k < 16; ++k)
                wt[v * 16 + k] = f2bf(Wo[k * VOC + v]);
        }
    }
}

// ---------------------------------------------------------------------------
// Kernel B: serial recurrence, pure-register; emits bf16 Hcat (hc2[pos][16]).
// ---------------------------------------------------------------------------
__global__ __launch_bounds__(512) void rnn_scan_kernel(
    const float* __restrict__ xpf, const float* __restrict__ xpb,
    const float* __restrict__ Whf, const float* __restrict__ Whb,
    const float* __restrict__ Hf0, const float* __restrict__ Hb0,
    unsigned short* __restrict__ hc2)
{
    const int dir = blockIdx.x;
    const int tid = threadIdx.x;
    const int b   = tid >> 3;
    const int h   = tid & 7;

    const float* Wh = dir ? Whb : Whf;
    const float* xp = (dir ? xpb : xpf) + (size_t)tid * SEQ;

    float wh[HD];
#pragma unroll
    for (int j = 0; j < HD; ++j) wh[j] = Wh[j * HD + h];

    float xs[SEQ];
    const f32x4* xp4 = (const f32x4*)xp;
#pragma unroll
    for (int q = 0; q < SEQ / 4; ++q) {
        f32x4 v = xp4[q];
        xs[4 * q + 0] = v.x; xs[4 * q + 1] = v.y;
        xs[4 * q + 2] = v.z; xs[4 * q + 3] = v.w;
    }

    float hcur = dir ? Hb0[h] : Hf0[h];
    const int koff = dir ? HD : 0;

#pragma unroll
    for (int t = 0; t < SEQ; ++t) {
        const int s = dir ? (SEQ - 1 - t) : t;
        hc2[(s * BSZ + b) * 16 + koff + h] = f2bf(hcur);   // previous state

        float acc = xs[t];
#pragma unroll
        for (int j = 0; j < HD; ++j)
            acc = fmaf(__shfl(hcur, j, 8), wh[j], acc);

        float e = __expf(2.0f * acc);
        hcur = (e - 1.0f) / (e + 1.0f);
    }
}

// ---------------------------------------------------------------------------
// Kernel C: partial exp-sums. Wave = (row-block rb, v-split vs); 25 v-tiles.
// MFMA 32x32x16 bf16 D layout: col=lane&31, row=(g&3)+8*(g>>2)+4*(lane>>5).
// ---------------------------------------------------------------------------
__global__ __launch_bounds__(256) void lse_partial_kernel(
    const unsigned short* __restrict__ hc2,
    const unsigned short* __restrict__ wt,
    const float* __restrict__ bo,
    float* __restrict__ partial)
{
    const int gw   = blockIdx.x * 4 + (threadIdx.x >> 6);   // global wave id
    const int rb   = gw / NVS;
    const int vs   = gw - rb * NVS;
    const int lane = threadIdx.x & 63;
    const int half = lane >> 5;
    const int lc   = lane & 31;

    const bf16x8 afrag = *(const bf16x8*)(hc2 + (size_t)(rb * 32 + lc) * 16 + half * 8);

    f32x16 zv;
#pragma unroll
    for (int i = 0; i < 16; ++i) zv[i] = 0.0f;

    float sacc[16];
#pragma unroll
    for (int g = 0; g < 16; ++g) sacc[g] = 0.0f;

    for (int t = 0; t < TPW; ++t) {
        const int v0 = (vs * TPW + t) * 32;
        const bf16x8 bfrag = *(const bf16x8*)(wt + (size_t)(v0 + lc) * 16 + half * 8);
        f32x16 d = __builtin_amdgcn_mfma_f32_32x32x16_bf16(afrag, bfrag, zv, 0, 0, 0);
        const float bov = bo[v0 + lc];
#pragma unroll
        for (int g = 0; g < 16; ++g)
            sacc[g] += __expf(d[g] + bov);
    }

    // reduce each sacc[g] across the 32 lanes of this half
#pragma unroll
    for (int g = 0; g < 16; ++g) {
        float s = sacc[g];
        s += __shfl_xor(s, 1, 32);
        s += __shfl_xor(s, 2, 32);
        s += __shfl_xor(s, 4, 32);
        s += __shfl_xor(s, 8, 32);
        s += __shfl_xor(s, 16, 32);
        sacc[g] = s;
    }

    if (lc == 0) {
#pragma unroll
        for (int g = 0; g < 16; ++g) {
            const int row = (g & 3) + 8 * (g >> 2) + 4 * half;
            partial[(size_t)(rb * 32 + row) * NVS + vs] = sacc[g];
        }
    }
}

// ---------------------------------------------------------------------------
// Kernel D: lse[row] = log( sum_vs partial[row][vs] )
// ---------------------------------------------------------------------------
__global__ __launch_bounds__(256) void lse_reduce_kernel(
    const float* __restrict__ partial, float* __restrict__ lse)
{
    const int row = blockIdx.x * 256 + threadIdx.x;
    if (row >= NPOS) return;
    const f32x4* p4 = (const f32x4*)(partial + (size_t)row * NVS);
    float s = 0.0f;
#pragma unroll
    for (int q = 0; q < NVS / 4; ++q) {
        f32x4 v = p4[q];
        s += v.x + v.y + v.z + v.w;
    }
    lse[row] = logf(s);
}

// ---------------------------------------------------------------------------
// Kernel E: out = logits - lse via MFMA; output routed through a per-wave
// LDS tile so stores are wide contiguous runs instead of scattered 128 B.
// Wave = (rb, vs) as before; 25 tiles processed as 5 groups of 5.
//   per group: 5x { MFMA -> val = d + bo - lse -> lbuf[32][160] }
//   then 20x  { ds_read_b128 -> nontemporal dwordx4 store } : 640 B runs/row,
//   1 KB per store instruction (fill-kernel-class write pattern).
// Values bit-identical to the scalar-store version.
// ---------------------------------------------------------------------------
__global__ __launch_bounds__(256) void out_mfma_kernel(
    const unsigned short* __restrict__ hc2,
    const unsigned short* __restrict__ wt,
    const float* __restrict__ bo,
    const float* __restrict__ lse,
    float* __restrict__ out)
{
    __shared__ float lbuf[4][32][160];   // 80 KB; per-wave private slice

    const int w    = threadIdx.x >> 6;
    const int gw   = blockIdx.x * 4 + w;
    const int rb   = gw / NVS;
    const int vs   = gw - rb * NVS;
    const int lane = threadIdx.x & 63;
    const int half = lane >> 5;
    const int lc   = lane & 31;

    const bf16x8 afrag = *(const bf16x8*)(hc2 + (size_t)(rb * 32 + lc) * 16 + half * 8);

    f32x16 zv;
#pragma unroll
    for (int i = 0; i < 16; ++i) zv[i] = 0.0f;

    // per-lane lse for its 16 (reg) rows
    float lse16[16];
#pragma unroll
    for (int g = 0; g < 16; ++g) {
        const int row = (g & 3) + 8 * (g >> 2) + 4 * half;
        lse16[g] = lse[rb * 32 + row];
    }

    for (int grp = 0; grp < 5; ++grp) {
        // ---- compute 5 tiles into the LDS staging tile ----
#pragma unroll
        for (int t5 = 0; t5 < 5; ++t5) {
            const int v0 = (vs * TPW + grp * 5 + t5) * 32;
            const bf16x8 bfrag = *(const bf16x8*)(wt + (size_t)(v0 + lc) * 16 + half * 8);
            f32x16 d = __builtin_amdgcn_mfma_f32_32x32x16_bf16(afrag, bfrag, zv, 0, 0, 0);
            const float bov = bo[v0 + lc];
#pragma unroll
            for (int g = 0; g < 16; ++g) {
                const int row = (g & 3) + 8 * (g >> 2) + 4 * half;
                lbuf[w][row][t5 * 32 + lc] = d[g] + bov - lse16[g];
            }
        }
        // ---- stream the 32x160 tile out as wide contiguous nt stores ----
        // (same-wave LDS write->read dependency; compiler inserts lgkmcnt)
        const size_t obase = (size_t)(rb * 32) * VOC
                           + (size_t)(vs * TPW + grp * 5) * 32;
#pragma unroll
        for (int i = 0; i < 20; ++i) {
            const int q   = i * 64 + lane;     // quad index 0..1279
            const int row = q / 40;            // 40 quads (160 floats) per row
            const int c   = q - row * 40;
            const f32x4 v4 = *(const f32x4*)&lbuf[w][row][c * 4];
            __builtin_nontemporal_store(
                v4, (f32x4*)(out + obase + (size_t)row * VOC + c * 4));
        }
    }
}

extern "C" void kernel_launch(void* const* d_in, const int* in_sizes, int n_in,
                              void* d_out, int out_size, void* d_ws, size_t ws_size,
                              hipStream_t stream)
{
    const int*   idx    = (const int*)  d_in[0];
    const float* lookup = (const float*)d_in[1];
    const float* Wxf    = (const float*)d_in[2];
    const float* Whf    = (const float*)d_in[3];
    const float* Wxb    = (const float*)d_in[4];
    const float* Whb    = (const float*)d_in[5];
    const float* Wo     = (const float*)d_in[6];
    const float* Hf0    = (const float*)d_in[7];
    const float* Hb0    = (const float*)d_in[8];
    const float* bf1    = (const float*)d_in[9];
    const float* bf2    = (const float*)d_in[10];
    const float* bb1    = (const float*)d_in[11];
    const float* bb2    = (const float*)d_in[12];
    const float* bo     = (const float*)d_in[13];
    float* out = (float*)d_out;

    // workspace layout (all 16B-aligned)
    char* ws = (char*)d_ws;
    float*          xpf     = (float*)ws;          ws += BSZ * HD * SEQ * 4;      // 256 KB
    float*          xpb     = (float*)ws;          ws += BSZ * HD * SEQ * 4;      // 256 KB
    unsigned short* hc2     = (unsigned short*)ws; ws += NPOS * 16 * 2;           // 256 KB
    unsigned short* wt      = (unsigned short*)ws; ws += VOC * 16 * 2;            // 1 MB
    float*          partial = (float*)ws;          ws += (size_t)NPOS * NVS * 4;  // 1.31 MB
    float*          lse     = (float*)ws;          ws += NPOS * 4;                // 32 KB

    hipLaunchKernelGGL(prep_kernel, dim3(32 + VOC / 256), dim3(256), 0, stream,
                       idx, lookup, Wxf, Wxb, bf1, bf2, bb1, bb2, Wo,
                       xpf, xpb, wt);
    hipLaunchKernelGGL(rnn_scan_kernel, dim3(2), dim3(512), 0, stream,
                       xpf, xpb, Whf, Whb, Hf0, Hb0, hc2);
    hipLaunchKernelGGL(lse_partial_kernel, dim3(NRB * NVS / 4), dim3(256), 0, stream,
                       hc2, wt, bo, partial);
    hipLaunchKernelGGL(lse_reduce_kernel, dim3(NPOS / 256), dim3(256), 0, stream,
                       partial, lse);
    hipLaunchKernelGGL(out_mfma_kernel, dim3(NRB * NVS / 4), dim3(256), 0, stream,
                       hc2, wt, bo, lse, out);
}

// Round 11
// 279.673 us; speedup vs baseline: 1.4879x; 1.0265x over previous
//
#include <hip/hip_runtime.h>

#define SEQ 128
#define BSZ 64
#define EMB 32
#define HD  8
#define VOC 32000
#define NPOS (SEQ * BSZ)          // 8192 positions
#define NRB  (NPOS / 32)          // 256 row-blocks of 32 positions
#define NVS  40                   // v-splits; 1000 v-tiles = 40 * 25
#define TPW  25                   // v-tiles per wave

typedef float f32x4  __attribute__((ext_vector_type(4)));
typedef short bf16x8 __attribute__((ext_vector_type(8)));
typedef float f32x16 __attribute__((ext_vector_type(16)));

// round-to-nearest-even f32 -> bf16 bits
__device__ __forceinline__ unsigned short f2bf(float f) {
    union { float f; unsigned int u; } x; x.f = f;
    unsigned int r = x.u + 0x7fffu + ((x.u >> 16) & 1u);
    return (unsigned short)(r >> 16);
}

// ---------------------------------------------------------------------------
// Kernel A (fused prep):
//  blocks [0,32):   xproj = lookup[idx] @ Wx + b1 + b2 (both dirs),
//                   thread-contiguous, backward copy time-reversed.
//  blocks [32,157): wt = bf16(Wo^T)  [32000][16]
// ---------------------------------------------------------------------------
__global__ __launch_bounds__(256) void prep_kernel(
    const int*   __restrict__ idx,
    const float* __restrict__ lookup,
    const float* __restrict__ Wxf, const float* __restrict__ Wxb,
    const float* __restrict__ bf1, const float* __restrict__ bf2,
    const float* __restrict__ bb1, const float* __restrict__ bb2,
    const float* __restrict__ Wo,
    float* __restrict__ xpf, float* __restrict__ xpb,
    unsigned short* __restrict__ wt)
{
    if (blockIdx.x < 32) {
        const int i = blockIdx.x * 256 + threadIdx.x;   // flat (s*B + b)
        const int s = i >> 6;
        const int b = i & 63;

        const float* xr = lookup + (size_t)idx[i] * EMB;
        float x[EMB];
#pragma unroll
        for (int e = 0; e < EMB; ++e) x[e] = xr[e];

#pragma unroll
        for (int h = 0; h < HD; ++h) {
            float af = bf1[h] + bf2[h];
            float ab = bb1[h] + bb2[h];
#pragma unroll
            for (int e = 0; e < EMB; ++e) {
                af = fmaf(x[e], Wxf[e * HD + h], af);
                ab = fmaf(x[e], Wxb[e * HD + h], ab);
            }
            xpf[(b * HD + h) * SEQ + s]             = af;
            xpb[(b * HD + h) * SEQ + (SEQ - 1 - s)] = ab;
        }
    } else {
        const int v = (blockIdx.x - 32) * 256 + threadIdx.x;
        if (v < VOC) {
#pragma unroll
            for (int k = 0; k < 16; ++k)
                wt[v * 16 + k] = f2bf(Wo[k * VOC + v]);
        }
    }
}

// ---------------------------------------------------------------------------
// Kernel B: serial recurrence, pure-register; emits bf16 Hcat (hc2[pos][16]).
// ---------------------------------------------------------------------------
__global__ __launch_bounds__(512) void rnn_scan_kernel(
    const float* __restrict__ xpf, const float* __restrict__ xpb,
    const float* __restrict__ Whf, const float* __restrict__ Whb,
    const float* __restrict__ Hf0, const float* __restrict__ Hb0,
    unsigned short* __restrict__ hc2)
{
    const int dir = blockIdx.x;
    const int tid = threadIdx.x;
    const int b   = tid >> 3;
    const int h   = tid & 7;

    const float* Wh = dir ? Whb : Whf;
    const float* xp = (dir ? xpb : xpf) + (size_t)tid * SEQ;

    float wh[HD];
#pragma unroll
    for (int j = 0; j < HD; ++j) wh[j] = Wh[j * HD + h];

    float xs[SEQ];
    const f32x4* xp4 = (const f32x4*)xp;
#pragma unroll
    for (int q = 0; q < SEQ / 4; ++q) {
        f32x4 v = xp4[q];
        xs[4 * q + 0] = v.x; xs[4 * q + 1] = v.y;
        xs[4 * q + 2] = v.z; xs[4 * q + 3] = v.w;
    }

    float hcur = dir ? Hb0[h] : Hf0[h];
    const int koff = dir ? HD : 0;

#pragma unroll
    for (int t = 0; t < SEQ; ++t) {
        const int s = dir ? (SEQ - 1 - t) : t;
        hc2[(s * BSZ + b) * 16 + koff + h] = f2bf(hcur);   // previous state

        float acc = xs[t];
#pragma unroll
        for (int j = 0; j < HD; ++j)
            acc = fmaf(__shfl(hcur, j, 8), wh[j], acc);

        float e = __expf(2.0f * acc);
        hcur = (e - 1.0f) / (e + 1.0f);
    }
}

// ---------------------------------------------------------------------------
// Kernel C: partial exp-sums. Wave = (row-block rb, v-split vs); 25 v-tiles.
// MFMA 32x32x16 bf16 D layout: col=lane&31, row=(g&3)+8*(g>>2)+4*(lane>>5).
// ---------------------------------------------------------------------------
__global__ __launch_bounds__(256) void lse_partial_kernel(
    const unsigned short* __restrict__ hc2,
    const unsigned short* __restrict__ wt,
    const float* __restrict__ bo,
    float* __restrict__ partial)
{
    const int gw   = blockIdx.x * 4 + (threadIdx.x >> 6);   // global wave id
    const int rb   = gw / NVS;
    const int vs   = gw - rb * NVS;
    const int lane = threadIdx.x & 63;
    const int half = lane >> 5;
    const int lc   = lane & 31;

    const bf16x8 afrag = *(const bf16x8*)(hc2 + (size_t)(rb * 32 + lc) * 16 + half * 8);

    f32x16 zv;
#pragma unroll
    for (int i = 0; i < 16; ++i) zv[i] = 0.0f;

    float sacc[16];
#pragma unroll
    for (int g = 0; g < 16; ++g) sacc[g] = 0.0f;

    for (int t = 0; t < TPW; ++t) {
        const int v0 = (vs * TPW + t) * 32;
        const bf16x8 bfrag = *(const bf16x8*)(wt + (size_t)(v0 + lc) * 16 + half * 8);
        f32x16 d = __builtin_amdgcn_mfma_f32_32x32x16_bf16(afrag, bfrag, zv, 0, 0, 0);
        const float bov = bo[v0 + lc];
#pragma unroll
        for (int g = 0; g < 16; ++g)
            sacc[g] += __expf(d[g] + bov);
    }

    // reduce each sacc[g] across the 32 lanes of this half
#pragma unroll
    for (int g = 0; g < 16; ++g) {
        float s = sacc[g];
        s += __shfl_xor(s, 1, 32);
        s += __shfl_xor(s, 2, 32);
        s += __shfl_xor(s, 4, 32);
        s += __shfl_xor(s, 8, 32);
        s += __shfl_xor(s, 16, 32);
        sacc[g] = s;
    }

    if (lc == 0) {
#pragma unroll
        for (int g = 0; g < 16; ++g) {
            const int row = (g & 3) + 8 * (g >> 2) + 4 * half;
            partial[(size_t)(rb * 32 + row) * NVS + vs] = sacc[g];
        }
    }
}

// ---------------------------------------------------------------------------
// Kernel D: lse[row] = log( sum_vs partial[row][vs] )
// ---------------------------------------------------------------------------
__global__ __launch_bounds__(256) void lse_reduce_kernel(
    const float* __restrict__ partial, float* __restrict__ lse)
{
    const int row = blockIdx.x * 256 + threadIdx.x;
    if (row >= NPOS) return;
    const f32x4* p4 = (const f32x4*)(partial + (size_t)row * NVS);
    float s = 0.0f;
#pragma unroll
    for (int q = 0; q < NVS / 4; ++q) {
        f32x4 v = p4[q];
        s += v.x + v.y + v.z + v.w;
    }
    lse[row] = logf(s);
}

// ---------------------------------------------------------------------------
// Kernel E: out = logits - lse via MFMA; output staged through a per-wave
// LDS tile, then streamed out as wide contiguous PLAIN stores (1 KB per
// store instruction — the fill-kernel-class pattern that measures 6.8 TB/s).
// nt was dropped: wt re-fetch is bounded by ~131 MB even with zero L2 hits,
// while nt stores appear to cap write throughput (~4.3 vs 6.8 TB/s).
// ---------------------------------------------------------------------------
__global__ __launch_bounds__(256) void out_mfma_kernel(
    const unsigned short* __restrict__ hc2,
    const unsigned short* __restrict__ wt,
    const float* __restrict__ bo,
    const float* __restrict__ lse,
    float* __restrict__ out)
{
    __shared__ float lbuf[4][32][160];   // 80 KB; per-wave private slice

    const int w    = threadIdx.x >> 6;
    const int gw   = blockIdx.x * 4 + w;
    const int rb   = gw / NVS;
    const int vs   = gw - rb * NVS;
    const int lane = threadIdx.x & 63;
    const int half = lane >> 5;
    const int lc   = lane & 31;

    const bf16x8 afrag = *(const bf16x8*)(hc2 + (size_t)(rb * 32 + lc) * 16 + half * 8);

    f32x16 zv;
#pragma unroll
    for (int i = 0; i < 16; ++i) zv[i] = 0.0f;

    // per-lane lse for its 16 (reg) rows
    float lse16[16];
#pragma unroll
    for (int g = 0; g < 16; ++g) {
        const int row = (g & 3) + 8 * (g >> 2) + 4 * half;
        lse16[g] = lse[rb * 32 + row];
    }

    for (int grp = 0; grp < 5; ++grp) {
        // ---- compute 5 tiles into the LDS staging tile ----
#pragma unroll
        for (int t5 = 0; t5 < 5; ++t5) {
            const int v0 = (vs * TPW + grp * 5 + t5) * 32;
            const bf16x8 bfrag = *(const bf16x8*)(wt + (size_t)(v0 + lc) * 16 + half * 8);
            f32x16 d = __builtin_amdgcn_mfma_f32_32x32x16_bf16(afrag, bfrag, zv, 0, 0, 0);
            const float bov = bo[v0 + lc];
#pragma unroll
            for (int g = 0; g < 16; ++g) {
                const int row = (g & 3) + 8 * (g >> 2) + 4 * half;
                lbuf[w][row][t5 * 32 + lc] = d[g] + bov - lse16[g];
            }
        }
        // ---- stream the 32x160 tile out as wide contiguous plain stores ----
        // (same-wave LDS write->read dependency; compiler inserts lgkmcnt)
        const size_t obase = (size_t)(rb * 32) * VOC
                           + (size_t)(vs * TPW + grp * 5) * 32;
#pragma unroll
        for (int i = 0; i < 20; ++i) {
            const int q   = i * 64 + lane;     // quad index 0..1279
            const int row = q / 40;            // 40 quads (160 floats) per row
            const int c   = q - row * 40;
            const f32x4 v4 = *(const f32x4*)&lbuf[w][row][c * 4];
            *(f32x4*)(out + obase + (size_t)row * VOC + c * 4) = v4;
        }
    }
}

extern "C" void kernel_launch(void* const* d_in, const int* in_sizes, int n_in,
                              void* d_out, int out_size, void* d_ws, size_t ws_size,
                              hipStream_t stream)
{
    const int*   idx    = (const int*)  d_in[0];
    const float* lookup = (const float*)d_in[1];
    const float* Wxf    = (const float*)d_in[2];
    const float* Whf    = (const float*)d_in[3];
    const float* Wxb    = (const float*)d_in[4];
    const float* Whb    = (const float*)d_in[5];
    const float* Wo     = (const float*)d_in[6];
    const float* Hf0    = (const float*)d_in[7];
    const float* Hb0    = (const float*)d_in[8];
    const float* bf1    = (const float*)d_in[9];
    const float* bf2    = (const float*)d_in[10];
    const float* bb1    = (const float*)d_in[11];
    const float* bb2    = (const float*)d_in[12];
    const float* bo     = (const float*)d_in[13];
    float* out = (float*)d_out;

    // workspace layout (all 16B-aligned)
    char* ws = (char*)d_ws;
    float*          xpf     = (float*)ws;          ws += BSZ * HD * SEQ * 4;      // 256 KB
    float*          xpb     = (float*)ws;          ws += BSZ * HD * SEQ * 4;      // 256 KB
    unsigned short* hc2     = (unsigned short*)ws; ws += NPOS * 16 * 2;           // 256 KB
    unsigned short* wt      = (unsigned short*)ws; ws += VOC * 16 * 2;            // 1 MB
    float*          partial = (float*)ws;          ws += (size_t)NPOS * NVS * 4;  // 1.31 MB
    float*          lse     = (float*)ws;          ws += NPOS * 4;                // 32 KB

    hipLaunchKernelGGL(prep_kernel, dim3(32 + VOC / 256), dim3(256), 0, stream,
                       idx, lookup, Wxf, Wxb, bf1, bf2, bb1, bb2, Wo,
                       xpf, xpb, wt);
    hipLaunchKernelGGL(rnn_scan_kernel, dim3(2), dim3(512), 0, stream,
                       xpf, xpb, Whf, Whb, Hf0, Hb0, hc2);
    hipLaunchKernelGGL(lse_partial_kernel, dim3(NRB * NVS / 4), dim3(256), 0, stream,
                       hc2, wt, bo, partial);
    hipLaunchKernelGGL(lse_reduce_kernel, dim3(NPOS / 256), dim3(256), 0, stream,
                       partial, lse);
    hipLaunchKernelGGL(out_mfma_kernel, dim3(NRB * NVS / 4), dim3(256), 0, stream,
                       hc2, wt, bo, lse, out);
}